// Round 1
// baseline (1474.794 us; speedup 1.0000x reference)
//
#include <hip/hip_runtime.h>

typedef unsigned short u16;
typedef __attribute__((ext_vector_type(8))) short short8;
typedef __attribute__((ext_vector_type(4))) float f32x4;

// Problem constants
#define BB 4
#define SS 1024
#define HIDN 4096
#define HH 32
#define HKV 8
#define DD 128
#define RR 16
#define MM (BB * SS)   // 4096 token rows

// ---------- helpers ----------
__device__ __forceinline__ u16 f2bf(float f) {
    unsigned u = __builtin_bit_cast(unsigned, f);
    unsigned r = u + 0x7FFFu + ((u >> 16) & 1u);   // RNE (no NaN inputs here)
    return (u16)(r >> 16);
}
__device__ __forceinline__ float bf2f(u16 u) {
    unsigned v = ((unsigned)u) << 16;
    return __builtin_bit_cast(float, v);
}

// ---------- 1. fp32 -> bf16 cast ----------
__global__ void cast_kernel(const float* __restrict__ src, u16* __restrict__ dst, int n4) {
    int i = blockIdx.x * blockDim.x + threadIdx.x;
    int stride = gridDim.x * blockDim.x;
    for (; i < n4; i += stride) {
        float4 v = reinterpret_cast<const float4*>(src)[i];
        ushort4 o;
        o.x = f2bf(v.x); o.y = f2bf(v.y); o.z = f2bf(v.z); o.w = f2bf(v.w);
        reinterpret_cast<ushort4*>(dst)[i] = o;
    }
}

// ---------- 2. LoRA down-proj: t[b,s,r] = sum_i X[b,s,i] * A[b,r,i] ----------
// one block per token row; 3 A matrices share the X read
__global__ __launch_bounds__(256) void lora_t3_kernel(
        const float* __restrict__ X,
        const float* __restrict__ Aq, const float* __restrict__ Ak, const float* __restrict__ Av,
        float* __restrict__ tq, float* __restrict__ tk, float* __restrict__ tv) {
    int row = blockIdx.x;          // 0..4095
    int b = row >> 10;
    int tid = threadIdx.x;
    const float* Am[3] = { Aq + (size_t)b * RR * HIDN,
                           Ak + (size_t)b * RR * HIDN,
                           Av + (size_t)b * RR * HIDN };
    float acc[48];
#pragma unroll
    for (int j = 0; j < 48; j++) acc[j] = 0.f;
    const float* Xr = X + (size_t)row * HIDN;
    for (int i = tid; i < HIDN; i += 256) {
        float x = Xr[i];
#pragma unroll
        for (int m = 0; m < 3; m++) {
            const float* Ab = Am[m];
#pragma unroll
            for (int r = 0; r < RR; r++)
                acc[m * RR + r] += x * Ab[(size_t)r * HIDN + i];
        }
    }
#pragma unroll
    for (int j = 0; j < 48; j++) {
        float v = acc[j];
#pragma unroll
        for (int off = 1; off < 64; off <<= 1) v += __shfl_xor(v, off, 64);
        acc[j] = v;
    }
    __shared__ float red[48];
    if (tid < 48) red[tid] = 0.f;
    __syncthreads();
    if ((tid & 63) == 0) {
#pragma unroll
        for (int j = 0; j < 48; j++) atomicAdd(&red[j], acc[j]);
    }
    __syncthreads();
    if (tid < 16)      tq[(size_t)row * RR + tid]        = red[tid];
    else if (tid < 32) tk[(size_t)row * RR + (tid - 16)] = red[tid];
    else if (tid < 48) tv[(size_t)row * RR + (tid - 32)] = red[tid];
}

// variant: bf16 input, single A matrix (for the O LoRA)
__global__ __launch_bounds__(256) void lora_t1_kernel(
        const u16* __restrict__ Xb, const float* __restrict__ Ao, float* __restrict__ to) {
    int row = blockIdx.x;
    int b = row >> 10;
    int tid = threadIdx.x;
    const float* Ab = Ao + (size_t)b * RR * HIDN;
    float acc[16];
#pragma unroll
    for (int j = 0; j < 16; j++) acc[j] = 0.f;
    const u16* Xr = Xb + (size_t)row * HIDN;
    for (int i = tid; i < HIDN; i += 256) {
        float x = bf2f(Xr[i]);
#pragma unroll
        for (int r = 0; r < RR; r++) acc[r] += x * Ab[(size_t)r * HIDN + i];
    }
#pragma unroll
    for (int j = 0; j < 16; j++) {
        float v = acc[j];
#pragma unroll
        for (int off = 1; off < 64; off <<= 1) v += __shfl_xor(v, off, 64);
        acc[j] = v;
    }
    __shared__ float red[16];
    if (tid < 16) red[tid] = 0.f;
    __syncthreads();
    if ((tid & 63) == 0) {
#pragma unroll
        for (int j = 0; j < 16; j++) atomicAdd(&red[j], acc[j]);
    }
    __syncthreads();
    if (tid < 16) to[(size_t)row * RR + tid] = red[tid];
}

// ---------- 3. GEMM  C[m,n] = sum_k Xb[m,k]*Wb[n,k]  + LoRA-B epilogue ----------
// 128x128 tile, BK=32, 4 waves (2x2), each wave 4x4 of 16x16x32 MFMA
#define LDA 40   // padded LDS row stride (bf16 elems); 16B-aligned, 2-way banks
__global__ __launch_bounds__(256) void gemm_bt_lora(
        const u16* __restrict__ Xb, const u16* __restrict__ Wb,
        const float* __restrict__ T,  const float* __restrict__ Bl,
        void* __restrict__ outp, int N, int out_f32) {
    const int K = HIDN;
    __shared__ __attribute__((aligned(16))) u16 Als[128 * LDA];
    __shared__ __attribute__((aligned(16))) u16 Bls[128 * LDA];
    int tid = threadIdx.x;
    int wave = tid >> 6, lane = tid & 63;
    int quad = lane >> 4, l15 = lane & 15;
    int wm = wave >> 1, wn = wave & 1;
    int m0 = blockIdx.y * 128, n0 = blockIdx.x * 128;

    f32x4 acc[4][4] = {};
    int r0 = tid >> 2;            // staging row 0..63
    int c0 = (tid & 3) * 8;       // staging col {0,8,16,24}

    for (int k0 = 0; k0 < K; k0 += 32) {
        *(uint4*)&Als[(r0)      * LDA + c0] = *(const uint4*)&Xb[(size_t)(m0 + r0)      * K + k0 + c0];
        *(uint4*)&Als[(r0 + 64) * LDA + c0] = *(const uint4*)&Xb[(size_t)(m0 + r0 + 64) * K + k0 + c0];
        *(uint4*)&Bls[(r0)      * LDA + c0] = *(const uint4*)&Wb[(size_t)(n0 + r0)      * K + k0 + c0];
        *(uint4*)&Bls[(r0 + 64) * LDA + c0] = *(const uint4*)&Wb[(size_t)(n0 + r0 + 64) * K + k0 + c0];
        __syncthreads();
        short8 af[4], bfr[4];
#pragma unroll
        for (int mi = 0; mi < 4; mi++)
            af[mi] = *(const short8*)&Als[(wm * 64 + mi * 16 + l15) * LDA + quad * 8];
#pragma unroll
        for (int ni = 0; ni < 4; ni++)
            bfr[ni] = *(const short8*)&Bls[(wn * 64 + ni * 16 + l15) * LDA + quad * 8];
#pragma unroll
        for (int mi = 0; mi < 4; mi++)
#pragma unroll
            for (int ni = 0; ni < 4; ni++)
                acc[mi][ni] = __builtin_amdgcn_mfma_f32_16x16x32_bf16(af[mi], bfr[ni], acc[mi][ni], 0, 0, 0);
        __syncthreads();
    }

    // epilogue: + sum_r T[row,r]*Bl[b,col,r], store bf16 or fp32
    int bidx = m0 >> 10;
    const float* BlB = Bl + (size_t)bidx * N * RR;
#pragma unroll
    for (int mi = 0; mi < 4; mi++) {
#pragma unroll
        for (int r = 0; r < 4; r++) {
            int row = m0 + wm * 64 + mi * 16 + quad * 4 + r;
            const float* Tr = T + (size_t)row * RR;
            float trv[16];
#pragma unroll
            for (int rr = 0; rr < 16; rr++) trv[rr] = Tr[rr];
#pragma unroll
            for (int ni = 0; ni < 4; ni++) {
                int col = n0 + wn * 64 + ni * 16 + l15;
                const float* Bc = BlB + (size_t)col * RR;
                float add = 0.f;
#pragma unroll
                for (int rr = 0; rr < 16; rr++) add += trv[rr] * Bc[rr];
                float v = acc[mi][ni][r] + add;
                if (out_f32) ((float*)outp)[(size_t)row * N + col] = v;
                else         ((u16*)outp)[(size_t)row * N + col]  = f2bf(v);
            }
        }
    }
}

// ---------- 4. RoPE, in place on bf16 (B,S,nh,D) ----------
__global__ void rope_kernel(u16* __restrict__ x, int nh) {
    int idx = blockIdx.x * 256 + threadIdx.x;
    int total = BB * SS * nh * (DD / 2);
    if (idx >= total) return;
    int d = idx & 63;
    int t = idx >> 6;                    // (b*S+s)*nh + h
    int pos = (t / nh) & (SS - 1);
    size_t base = (size_t)t * DD;
    float inv = __expf(-(float)d * (9.210340371976184f / 64.0f));  // theta^-(d/64)
    float ang = (float)pos * inv;
    float c = cosf(ang), s = sinf(ang);
    float x1 = bf2f(x[base + d]);
    float x2 = bf2f(x[base + 64 + d]);
    x[base + d]      = f2bf(x1 * c - x2 * s);
    x[base + 64 + d] = f2bf(x2 * c + x1 * s);
}

// ---------- 5. causal flash attention ----------
// block = 4 waves; BQ=64 (16 q-rows/wave), BK=32; GQA h->h/4
#define KLD 136   // K tile LDS stride
#define VLD 130   // V tile LDS stride (conflict-free transposed reads)
#define PLD 40    // P tile LDS stride
__global__ __launch_bounds__(256) void flash_kernel(
        const u16* __restrict__ Q, const u16* __restrict__ Kx, const u16* __restrict__ V,
        u16* __restrict__ Oa) {
    __shared__ __attribute__((aligned(16))) u16 Kls[32 * KLD];
    __shared__ __attribute__((aligned(16))) u16 Vls[32 * VLD];
    __shared__ __attribute__((aligned(16))) u16 Pls[4 * 16 * PLD];
    int tid = threadIdx.x;
    int wave = tid >> 6, lane = tid & 63;
    int quad = lane >> 4, l15 = lane & 15;
    int blk = blockIdx.x;               // ((b*H)+h)*(S/64)+qt
    int qt = blk & 15;
    int h  = (blk >> 4) & 31;
    int b  = blk >> 9;
    int hkv = h >> 2;
    int q0 = qt * 64;

    // Q fragments (A-operand): rows q0+wave*16+l15, k = kt*32+quad*8+j
    int qrow = q0 + wave * 16 + l15;
    const u16* qp = Q + ((size_t)(b * SS + qrow) * HH + h) * DD;
    short8 qf[4];
#pragma unroll
    for (int kt = 0; kt < 4; kt++) qf[kt] = *(const short8*)&qp[kt * 32 + quad * 8];

    f32x4 oacc[8] = {};
    float mrow[4], lrow[4];
#pragma unroll
    for (int r = 0; r < 4; r++) { mrow[r] = -3.0e38f; lrow[r] = 0.f; }
    const float scale = 0.08838834764831845f;   // 1/sqrt(128)

    int srow = tid >> 4;            // staging row 0..15
    int scol = (tid & 15) * 8;      // staging col
    int nkb = (q0 + 64) >> 5;
    for (int ib = 0; ib < nkb; ib++) {
        int kb = ib * 32;
        // stage K tile (row-major, stride KLD) and V tile (row-major, stride VLD)
        {
            size_t g0 = ((size_t)(b * SS + kb + srow) * HKV + hkv) * DD + scol;
            size_t g1 = ((size_t)(b * SS + kb + 16 + srow) * HKV + hkv) * DD + scol;
            *(uint4*)&Kls[srow * KLD + scol]        = *(const uint4*)&Kx[g0];
            *(uint4*)&Kls[(srow + 16) * KLD + scol] = *(const uint4*)&Kx[g1];
            uint4 v0 = *(const uint4*)&V[g0];
            uint4 v1 = *(const uint4*)&V[g1];
            const unsigned* w0 = (const unsigned*)&v0;
            const unsigned* w1 = (const unsigned*)&v1;
#pragma unroll
            for (int wj = 0; wj < 4; wj++) {
                *(unsigned*)&Vls[srow * VLD + scol + 2 * wj]        = w0[wj];
                *(unsigned*)&Vls[(srow + 16) * VLD + scol + 2 * wj] = w1[wj];
            }
        }
        __syncthreads();

        // scores: S[16x32] per wave via MFMA, C layout
        f32x4 sa[2] = {};
#pragma unroll
        for (int t2 = 0; t2 < 2; t2++)
#pragma unroll
            for (int kt = 0; kt < 4; kt++) {
                short8 kf = *(const short8*)&Kls[(t2 * 16 + l15) * KLD + kt * 32 + quad * 8];
                sa[t2] = __builtin_amdgcn_mfma_f32_16x16x32_bf16(qf[kt], kf, sa[t2], 0, 0, 0);
            }

        // online softmax per q-row (rows live on 16-lane groups)
#pragma unroll
        for (int r = 0; r < 4; r++) {
            int qpos = q0 + wave * 16 + quad * 4 + r;
            float s0 = sa[0][r] * scale;
            float s1 = sa[1][r] * scale;
            if (kb + l15 > qpos)      s0 = -1e30f;
            if (kb + 16 + l15 > qpos) s1 = -1e30f;
            float mx = fmaxf(s0, s1);
#pragma unroll
            for (int off = 1; off < 16; off <<= 1) mx = fmaxf(mx, __shfl_xor(mx, off, 64));
            float mnew = fmaxf(mrow[r], mx);
            float alpha = __expf(mrow[r] - mnew);
            float e0 = __expf(s0 - mnew);
            float e1 = __expf(s1 - mnew);
            float sum = e0 + e1;
#pragma unroll
            for (int off = 1; off < 16; off <<= 1) sum += __shfl_xor(sum, off, 64);
            lrow[r] = lrow[r] * alpha + sum;
            mrow[r] = mnew;
#pragma unroll
            for (int dt = 0; dt < 8; dt++) oacc[dt][r] *= alpha;
            Pls[wave * (16 * PLD) + (quad * 4 + r) * PLD + l15]      = f2bf(e0);
            Pls[wave * (16 * PLD) + (quad * 4 + r) * PLD + 16 + l15] = f2bf(e1);
        }

        // P (A-operand) from per-wave LDS; V B-operand via transposed scalar reads
        short8 pf = *(const short8*)&Pls[wave * (16 * PLD) + l15 * PLD + quad * 8];
#pragma unroll
        for (int dt = 0; dt < 8; dt++) {
            u16 vtmp[8];
#pragma unroll
            for (int j = 0; j < 8; j++)
                vtmp[j] = Vls[(quad * 8 + j) * VLD + dt * 16 + l15];
            short8 vf = *(const short8*)vtmp;
            oacc[dt] = __builtin_amdgcn_mfma_f32_16x16x32_bf16(pf, vf, oacc[dt], 0, 0, 0);
        }
        __syncthreads();
    }

    // epilogue: O /= l, store bf16 (B,S,H,D)
#pragma unroll
    for (int r = 0; r < 4; r++) {
        float inv = 1.0f / lrow[r];
        int orow = q0 + wave * 16 + quad * 4 + r;
        u16* op = Oa + ((size_t)(b * SS + orow) * HH + h) * DD;
#pragma unroll
        for (int dt = 0; dt < 8; dt++)
            op[dt * 16 + l15] = f2bf(oacc[dt][r] * inv);
    }
}

// ---------- launch ----------
extern "C" void kernel_launch(void* const* d_in, const int* in_sizes, int n_in,
                              void* d_out, int out_size, void* d_ws, size_t ws_size,
                              hipStream_t stream) {
    const float* X  = (const float*)d_in[0];
    const float* Wq = (const float*)d_in[1];
    const float* Wk = (const float*)d_in[2];
    const float* Wv = (const float*)d_in[3];
    const float* Wo = (const float*)d_in[4];
    const float* Aq = (const float*)d_in[5];
    const float* Bq = (const float*)d_in[6];
    const float* Ak = (const float*)d_in[7];
    const float* Bk = (const float*)d_in[8];
    const float* Av = (const float*)d_in[9];
    const float* Bv = (const float*)d_in[10];
    const float* Ao = (const float*)d_in[11];
    const float* Bo = (const float*)d_in[12];

    char* w = (char*)d_ws;
    auto take = [&](size_t bytes) {
        char* p = w;
        w += (bytes + 255) & ~(size_t)255;
        return p;
    };
    u16*   Xb  = (u16*)  take((size_t)MM * HIDN * 2);       // 33.5 MB (later aliased by attn)
    u16*   Wqb = (u16*)  take((size_t)HIDN * HIDN * 2);     // 33.5 MB
    u16*   Wkb = (u16*)  take((size_t)1024 * HIDN * 2);     // 8.4 MB
    u16*   Wvb = (u16*)  take((size_t)1024 * HIDN * 2);
    u16*   Wob = (u16*)  take((size_t)HIDN * HIDN * 2);
    float* tq  = (float*)take((size_t)MM * RR * 4);
    float* tk  = (float*)take((size_t)MM * RR * 4);
    float* tv  = (float*)take((size_t)MM * RR * 4);
    float* to  = (float*)take((size_t)MM * RR * 4);
    u16*   qb  = (u16*)  take((size_t)MM * HIDN * 2);
    u16*   kbuf= (u16*)  take((size_t)MM * 1024 * 2);
    u16*   vbuf= (u16*)  take((size_t)MM * 1024 * 2);
    u16*   attn = Xb;   // Xb dead after V GEMM; reuse for attention output

    // 1. casts
    cast_kernel<<<2048, 256, 0, stream>>>(X,  Xb,  MM * HIDN / 4);
    cast_kernel<<<2048, 256, 0, stream>>>(Wq, Wqb, HIDN * HIDN / 4);
    cast_kernel<<<1024, 256, 0, stream>>>(Wk, Wkb, 1024 * HIDN / 4);
    cast_kernel<<<1024, 256, 0, stream>>>(Wv, Wvb, 1024 * HIDN / 4);
    cast_kernel<<<2048, 256, 0, stream>>>(Wo, Wob, HIDN * HIDN / 4);
    // 2. LoRA down-projections for q,k,v
    lora_t3_kernel<<<MM, 256, 0, stream>>>(X, Aq, Ak, Av, tq, tk, tv);
    // 3. projections (bf16 out, LoRA fused)
    gemm_bt_lora<<<dim3(32, 32), 256, 0, stream>>>(Xb, Wqb, tq, Bq, qb,   HIDN, 0);
    gemm_bt_lora<<<dim3(8,  32), 256, 0, stream>>>(Xb, Wkb, tk, Bk, kbuf, 1024, 0);
    gemm_bt_lora<<<dim3(8,  32), 256, 0, stream>>>(Xb, Wvb, tv, Bv, vbuf, 1024, 0);
    // 4. RoPE in place
    rope_kernel<<<BB * SS * HH * 64 / 256, 256, 0, stream>>>(qb, HH);
    rope_kernel<<<BB * SS * HKV * 64 / 256, 256, 0, stream>>>(kbuf, HKV);
    // 5. attention
    flash_kernel<<<BB * HH * (SS / 64), 256, 0, stream>>>(qb, kbuf, vbuf, attn);
    // 6. LoRA-O down-projection + O GEMM -> fp32 out
    lora_t1_kernel<<<MM, 256, 0, stream>>>(attn, Ao, to);
    gemm_bt_lora<<<dim3(32, 32), 256, 0, stream>>>(attn, Wob, to, Bo, (void*)d_out, HIDN, 1);
}